// Round 4
// baseline (189.603 us; speedup 1.0000x reference)
//
#include <hip/hip_runtime.h>

// Attention_msa_TwoStream. Only v_cls (d_in[1]) feeds outputs (MLP/q/k dead).
// N=3200, H=8, d=64, C=512; fp32 I/O; bf16 MFMA internals.
// Pipeline (3 dispatches, no memset, no atomics):
//   k_prep  : per-(n,h) L2 norm; vnfull bf16 + vT/vnT transposes + x_ori.
//   k_rgemm : bid 0-7   -> G_h = sum_m V[m][d]*vn[m][k] (64x64x3200 NT GEMM,
//                         contiguous-K from vT/vnT, replaces 1.6M atomicAdds)
//             bid 8-332 -> R = 1/8 vn.vn^T upper-tri 128x128 tiles; 4-buf LDS,
//                         prefetch-2 counted vmcnt(8), ONE barrier per K-step;
//                         epilogue stages both (bi,bj)/(bj,bi) via LDS ->
//                         full 256B coalesced row writes.
//   k_fused : rows: Z/E row-sum + normalize -> out2 | tiles: X = vn.G - corr.

#define NN 3200
#define HEADS 8
#define DH 64
#define CC 512

typedef __attribute__((ext_vector_type(8))) short short8;   // 8 bf16
typedef __attribute__((ext_vector_type(4))) float f32x4;

static __device__ __forceinline__ unsigned short f2b(float f) {
  union { float f; unsigned u; } x; x.f = f;
  unsigned r = x.u + 0x7FFFu + ((x.u >> 16) & 1u);   // RTN-even
  return (unsigned short)(r >> 16);
}
static __device__ __forceinline__ float b2f(unsigned short s) {
  union { unsigned u; float f; } x; x.u = ((unsigned)s) << 16; return x.f;
}
static __device__ __forceinline__ short8 pack8(f32x4 lo, f32x4 hi) {
  short8 r;
  r[0] = (short)f2b(lo[0]); r[1] = (short)f2b(lo[1]);
  r[2] = (short)f2b(lo[2]); r[3] = (short)f2b(lo[3]);
  r[4] = (short)f2b(hi[0]); r[5] = (short)f2b(hi[1]);
  r[6] = (short)f2b(hi[2]); r[7] = (short)f2b(hi[3]);
  return r;
}

typedef const void __attribute__((address_space(1))) gvoid_t;
typedef void __attribute__((address_space(3))) lvoid_t;
static __device__ __forceinline__ void gl_lds16(const void* g, void* l) {
  __builtin_amdgcn_global_load_lds((gvoid_t*)g, (lvoid_t*)l, 16, 0, 0);
}

// ---------------------------------------------------------------------------
// k_prep: per-(n,h) L2 norm; vnfull bf16 (cached - heavy reuse), vT/vnT bf16
// transposes + x_ori f32 (non-temporal - streaming). No atomics, no MFMA.
__global__ __launch_bounds__(256) void k_prep(const float* __restrict__ v,
                                              unsigned short* __restrict__ vnfull,
                                              unsigned short* __restrict__ vT,
                                              unsigned short* __restrict__ vnT,
                                              float* __restrict__ out) {
  __shared__ unsigned short tileV[DH][72];   // [dim][row]
  __shared__ unsigned short tileN[DH][72];
  int h  = blockIdx.x & 7;
  int n0 = (int)(blockIdx.x >> 3) * 64;
  int j  = threadIdx.x & 63;       // dim within head
  int w  = threadIdx.x >> 6;       // wave = row group
  #pragma unroll
  for (int i = 0; i < 16; i++) {
    int n = n0 + w * 16 + i;
    float val = v[(size_t)n * CC + h * DH + j];
    float ss = val * val;
    #pragma unroll
    for (int off = 32; off >= 1; off >>= 1) ss += __shfl_xor(ss, off, 64);
    float inv = 1.0f / (sqrtf(ss) + 1e-8f);
    unsigned short un = f2b(val * inv);
    tileV[j][w * 16 + i] = f2b(val);
    tileN[j][w * 16 + i] = un;
    vnfull[(size_t)n * CC + h * DH + j] = un;
    __builtin_nontemporal_store(val, out + (size_t)n * (2 * CC) + CC + h * DH + j);
  }
  __syncthreads();
  #pragma unroll
  for (int i = 0; i < 16; i++) {
    int jj = w * 16 + i;
    __builtin_nontemporal_store(tileV[jj][j], vT  + ((size_t)h * DH + jj) * NN + n0 + j);
    __builtin_nontemporal_store(tileN[jj][j], vnT + ((size_t)h * DH + jj) * NN + n0 + j);
  }
}

// ---------------------------------------------------------------------------
// k_rgemm: bid 0-7: G_h (no atomics). bid 8-332: upper-tri R tiles.
__global__ __launch_bounds__(256) void k_rgemm(const unsigned short* __restrict__ vnfull,
                                               const unsigned short* __restrict__ vT,
                                               const unsigned short* __restrict__ vnT,
                                               float* __restrict__ Gf,
                                               unsigned short* __restrict__ Rg) {
  __shared__ __align__(16) unsigned short S[32768];   // 64 KB: 4-buf A/B, then tile
  #define AsB(b) (S + (b) * 4096)
  #define BsB(b) (S + 16384 + (b) * 4096)
  int bid = (int)blockIdx.x;
  int tid = threadIdx.x;
  int lane = tid & 63, quad = lane >> 4, l16 = lane & 15;

  if (bid < 8) {
    // ---- G_h = sum_m V[m][h*64+d] * vn[m][h*64+k], 64x64x3200 ------------
    // A[d][m] = vT[h*64+d][m] (contig m); B[k][m] = vnT[h*64+k][m] (contig m).
    int h = bid, w = tid >> 6;
    const unsigned short* aP = vT + (size_t)(h * DH + w * 16 + l16) * NN + quad * 8;
    const unsigned short* bP[4];
    #pragma unroll
    for (int ct = 0; ct < 4; ct++)
      bP[ct] = vnT + (size_t)(h * DH + ct * 16 + l16) * NN + quad * 8;
    f32x4 acc4[4];
    #pragma unroll
    for (int ct = 0; ct < 4; ct++) acc4[ct] = (f32x4){0.f, 0.f, 0.f, 0.f};
    #pragma unroll 1
    for (int m0 = 0; m0 < NN; m0 += 64) {
      short8 a0 = *(const short8*)(aP + m0);
      short8 a1 = *(const short8*)(aP + m0 + 32);
      #pragma unroll
      for (int ct = 0; ct < 4; ct++) {
        short8 b0 = *(const short8*)(bP[ct] + m0);
        short8 b1 = *(const short8*)(bP[ct] + m0 + 32);
        acc4[ct] = __builtin_amdgcn_mfma_f32_16x16x32_bf16(a0, b0, acc4[ct], 0, 0, 0);
        acc4[ct] = __builtin_amdgcn_mfma_f32_16x16x32_bf16(a1, b1, acc4[ct], 0, 0, 0);
      }
    }
    #pragma unroll
    for (int ct = 0; ct < 4; ct++)
      #pragma unroll
      for (int g = 0; g < 4; g++)
        Gf[(size_t)h * 4096 + (w * 16 + quad * 4 + g) * 64 + ct * 16 + l16] = acc4[ct][g];
    return;
  }
  bid -= 8;

  // upper-triangular (incl. diagonal) tile map: bid -> (bi, bj), bj >= bi
  int bi = 0;
  while (bid >= 25 - bi) { bid -= 25 - bi; bi++; }
  int bj = bi + bid;
  int n0 = bi * 128, m0 = bj * 128;
  int wv = tid >> 6, wr = wv >> 1, wc = wv & 1;

  const unsigned short* aG[2];
  const unsigned short* bG[2];
  int sl[2];
  #pragma unroll
  for (int t = 0; t < 2; t++) {
    int s = tid + t * 256;
    sl[t] = s;
    int row = ((s >> 5) << 3) | (s & 7), kc = (s >> 3) & 3;
    aG[t] = vnfull + (size_t)(n0 + row) * CC + kc * 8;
    bG[t] = vnfull + (size_t)(m0 + row) * CC + kc * 8;
  }

  int roA[4], roB[4];
  #pragma unroll
  for (int rt = 0; rt < 4; rt++) {
    int row = wr * 64 + rt * 16 + l16;
    roA[rt] = (row >> 3) * 256 + (row & 7) * 8;
  }
  #pragma unroll
  for (int ct = 0; ct < 4; ct++) {
    int row = wc * 64 + ct * 16 + l16;
    roB[ct] = (row >> 3) * 256 + (row & 7) * 8;
  }

  f32x4 acc[4][4];
  #pragma unroll
  for (int rt = 0; rt < 4; rt++)
    #pragma unroll
    for (int ct = 0; ct < 4; ct++) acc[rt][ct] = (f32x4){0.f, 0.f, 0.f, 0.f};

  // prologue: tiles 0 and 1 in flight (8 loads)
  #pragma unroll
  for (int t = 0; t < 2; t++) gl_lds16(aG[t], AsB(0) + sl[t] * 8);
  #pragma unroll
  for (int t = 0; t < 2; t++) gl_lds16(bG[t], BsB(0) + sl[t] * 8);
  #pragma unroll
  for (int t = 0; t < 2; t++) gl_lds16(aG[t] + 32, AsB(1) + sl[t] * 8);
  #pragma unroll
  for (int t = 0; t < 2; t++) gl_lds16(bG[t] + 32, BsB(1) + sl[t] * 8);

  // K-loop: prefetch distance 2, 4 buffers -> target buf was last read two
  // iterations ago, so its reads are sealed by the PREVIOUS opening barrier:
  // one s_barrier per K-step suffices.
  #pragma unroll 1
  for (int kk = 0; kk < 16; kk++) {
    int buf = kk & 3;
    if (kk < 14) {
      int ko = (kk + 2) * 32;
      int tb = (kk + 2) & 3;
      #pragma unroll
      for (int t = 0; t < 2; t++) gl_lds16(aG[t] + ko, AsB(tb) + sl[t] * 8);
      #pragma unroll
      for (int t = 0; t < 2; t++) gl_lds16(bG[t] + ko, BsB(tb) + sl[t] * 8);
      asm volatile("s_waitcnt vmcnt(8)" ::: "memory");   // tile kk landed
    } else if (kk == 14) {
      asm volatile("s_waitcnt vmcnt(4)" ::: "memory");
    } else {
      asm volatile("s_waitcnt vmcnt(0)" ::: "memory");
    }
    __builtin_amdgcn_s_barrier();            // all waves' tile-kk data visible
    __builtin_amdgcn_sched_barrier(0);
    short8 af[4], bf[4];
    #pragma unroll
    for (int rt = 0; rt < 4; rt++)
      af[rt] = *(const short8*)(AsB(buf) + roA[rt] + quad * 64);
    #pragma unroll
    for (int ct = 0; ct < 4; ct++)
      bf[ct] = *(const short8*)(BsB(buf) + roB[ct] + quad * 64);
    #pragma unroll
    for (int rt = 0; rt < 4; rt++)
      #pragma unroll
      for (int ct = 0; ct < 4; ct++)
        acc[rt][ct] = __builtin_amdgcn_mfma_f32_16x16x32_bf16(af[rt], bf[ct],
                                                              acc[rt][ct], 0, 0, 0);
  }
  __syncthreads();   // seal tile-15 reads before epilogue overwrites S

  // ---- epilogue A: orientation (n,m) — swizzled LDS stage + row writes ---
  // Tile element (r,c) at S[r*128 + ((c>>3)^quad)*8 + (c&7)], quad==(r>>2)&3.
  #pragma unroll
  for (int rt = 0; rt < 4; rt++) {
    int rbase = wr * 64 + rt * 16 + quad * 4;
    #pragma unroll
    for (int g = 0; g < 4; g++) {
      int r = rbase + g;
      int n = n0 + r;
      int bs = (n / 10) * 10;
      #pragma unroll
      for (int ct = 0; ct < 4; ct++) {
        int c = wc * 64 + ct * 16 + l16;
        int m = m0 + c;
        float R = acc[rt][ct][g] * 0.125f;
        float eR = __expf(R);
        bool sel = (R > 0.75f);
        bool zz = (m >= bs) & (m < bs + 9) & (m != n);
        float ef = zz ? 1.0f : eR;            // exp(0)=1
        S[r * 128 + (((c >> 3) ^ quad) << 3) + (c & 7)] = f2b(sel ? ef : -ef);
      }
    }
  }
  __syncthreads();
  {
    int r2b = wv * 32 + (lane >> 4);
    int s_ = lane & 15;
    #pragma unroll
    for (int i = 0; i < 8; i++) {
      int r2 = r2b + i * 4;
      int k = s_ ^ ((r2 >> 2) & 3);
      short8 vvv = *(const short8*)&S[r2 * 128 + s_ * 8];
      *(short8*)(Rg + (size_t)(n0 + r2) * NN + m0 + k * 8) = vvv;   // temporal: ride L3
    }
  }

  if (bi != bj) {
    // ---- epilogue B: orientation (m,n) — transposed staging --------------
    // Element (r,c) -> S[c*128 + ((r>>3)^l16)*8 + (r&7)], l16 == c&15.
    __syncthreads();
    #pragma unroll
    for (int rt = 0; rt < 4; rt++) {
      int rbase = wr * 64 + rt * 16 + quad * 4;
      #pragma unroll
      for (int g = 0; g < 4; g++) {
        int r = rbase + g;
        int n = n0 + r;
        #pragma unroll
        for (int ct = 0; ct < 4; ct++) {
          int c = wc * 64 + ct * 16 + l16;
          int m = m0 + c;
          int bsm = (m / 10) * 10;
          float R = acc[rt][ct][g] * 0.125f;
          float eR = __expf(R);
          bool sel = (R > 0.75f);
          bool zz = (n >= bsm) & (n < bsm + 9) & (m != n);
          float ef = zz ? 1.0f : eR;
          S[c * 128 + (((r >> 3) ^ l16) << 3) + (r & 7)] = f2b(sel ? ef : -ef);
        }
      }
    }
    __syncthreads();
    int r2b = wv * 32 + (lane >> 4);
    int s_ = lane & 15;
    #pragma unroll
    for (int i = 0; i < 8; i++) {
      int r2 = r2b + i * 4;                  // output row = m0 + r2
      int k = s_ ^ (r2 & 15);
      short8 vvv = *(const short8*)&S[r2 * 128 + s_ * 8];
      *(short8*)(Rg + (size_t)(m0 + r2) * NN + n0 + k * 8) = vvv;
    }
  }
  #undef AsB
  #undef BsB
}

// ---------------------------------------------------------------------------
// k_fused: blocks [0,800): out2 rows (wave-per-row Z/E sum + normalize);
//          blocks [800,1200): k_x tiles (X = vn.G - zone corr).
__global__ __launch_bounds__(256) void k_fused(const unsigned short* __restrict__ Rg,
                                               const unsigned short* __restrict__ vnfull,
                                               const float* __restrict__ Gf,
                                               const unsigned short* __restrict__ vT,
                                               float* __restrict__ out2,
                                               float* __restrict__ out) {
  int bid = (int)blockIdx.x;
  if (bid < 800) {
    // ---- softmax rows: n = bid*4 + wave ---------------------------------
    int w = threadIdx.x >> 6, lane = threadIdx.x & 63;
    int n = bid * 4 + w;
    const unsigned short* rp = Rg + (size_t)n * NN;
    short8 s[7];
    float z = 0.f, e = 0.f;
    #pragma unroll
    for (int i = 0; i < 7; i++) {
      int c = lane + i * 64;              // chunk of 8 bf16; 400 chunks/row
      if (c < 400) {
        s[i] = *(const short8*)(rp + c * 8);   // temporal: L3 hit after k_rgemm
        #pragma unroll
        for (int j = 0; j < 8; j++) {
          float val = b2f((unsigned short)s[i][j]);
          z += fabsf(val);
          e += fmaxf(val, 0.f);
        }
      }
    }
    #pragma unroll
    for (int off = 1; off <= 32; off <<= 1) {
      z += __shfl_xor(z, off, 64);
      e += __shfl_xor(e, off, 64);
    }
    float rd = 1.0f / (e + 1e-8f * z);
    float* op = out2 + (size_t)n * NN;
    #pragma unroll
    for (int i = 0; i < 7; i++) {
      int c = lane + i * 64;
      if (c < 400) {
        f32x4 o0, o1;
        #pragma unroll
        for (int j = 0; j < 4; j++) {
          float a = b2f((unsigned short)s[i][j]);
          o0[j] = (a > 0.f) ? a * rd : 0.f;
          float b = b2f((unsigned short)s[i][4 + j]);
          o1[j] = (b > 0.f) ? b * rd : 0.f;
        }
        __builtin_nontemporal_store(o0, (f32x4*)(op + c * 8));
        __builtin_nontemporal_store(o1, (f32x4*)(op + c * 8 + 4));
      }
    }
  } else {
    // ---- X tiles: X_h[n][d] = vn.G - zone correction --------------------
    bid -= 800;
    __shared__ __align__(16) unsigned short Sz[4][16][48];
    int hl   = threadIdx.x >> 6;
    int h    = (bid & 1) * 4 + hl;
    int lane = threadIdx.x & 63;
    int quad = lane >> 4, l16 = lane & 15;
    int n0 = (bid >> 1) * 16;
    int lo = (n0 / 10) * 10;                    // zone window [lo, lo+32)

    short8 aZ[2];
    #pragma unroll
    for (int kh = 0; kh < 2; kh++)
      aZ[kh] = *(const short8*)(vnfull + (size_t)(n0 + l16) * CC + h * DH + kh * 32 + quad * 8);

    #pragma unroll
    for (int ct = 0; ct < 2; ct++) {
      int rB = lo + ct * 16 + l16;
      int rC = rB < NN ? rB : NN - 1;           // clamp OOB (mask kills it)
      short8 b0 = *(const short8*)(vnfull + (size_t)rC * CC + h * DH + quad * 8);
      short8 b1 = *(const short8*)(vnfull + (size_t)rC * CC + h * DH + 32 + quad * 8);
      f32x4 cS = (f32x4){0.f, 0.f, 0.f, 0.f};
      cS = __builtin_amdgcn_mfma_f32_16x16x32_bf16(aZ[0], b0, cS, 0, 0, 0);
      cS = __builtin_amdgcn_mfma_f32_16x16x32_bf16(aZ[1], b1, cS, 0, 0, 0);
      int m = lo + ct * 16 + l16;
      #pragma unroll
      for (int g = 0; g < 4; g++) {
        int n = n0 + quad * 4 + g;
        int bs = (n / 10) * 10;
        bool keep = (m >= bs) & (m < bs + 9) & (m != n);
        Sz[hl][quad * 4 + g][ct * 16 + l16] = f2b(keep ? -cS[g] : 0.f);
      }
    }
    __syncthreads();

    f32x4 xr[4];
    #pragma unroll
    for (int nt = 0; nt < 4; nt++) {
      const float* gp = Gf + (size_t)h * 4096 + (nt * 16 + l16) * 64 + quad * 8;
      short8 g0 = pack8(*(const f32x4*)gp, *(const f32x4*)(gp + 4));
      short8 g1 = pack8(*(const f32x4*)(gp + 32), *(const f32x4*)(gp + 36));
      f32x4 cX = (f32x4){0.f, 0.f, 0.f, 0.f};
      cX = __builtin_amdgcn_mfma_f32_16x16x32_bf16(aZ[0], g0, cX, 0, 0, 0);
      cX = __builtin_amdgcn_mfma_f32_16x16x32_bf16(aZ[1], g1, cX, 0, 0, 0);
      xr[nt] = cX;
    }

    short8 aC = *(const short8*)&Sz[hl][l16][quad * 8];
    #pragma unroll
    for (int nt = 0; nt < 4; nt++) {
      short8 b = *(const short8*)(vT + (size_t)(h * DH + nt * 16 + l16) * NN + lo + quad * 8);
      xr[nt] = __builtin_amdgcn_mfma_f32_16x16x32_bf16(aC, b, xr[nt], 0, 0, 0);
    }

    #pragma unroll
    for (int nt = 0; nt < 4; nt++)
      #pragma unroll
      for (int g = 0; g < 4; g++)
        __builtin_nontemporal_store(xr[nt][g],
            out + (size_t)(n0 + quad * 4 + g) * (2 * CC) + h * DH + nt * 16 + l16);
  }
}

// ---------------------------------------------------------------------------
extern "C" void kernel_launch(void* const* d_in, const int* in_sizes, int n_in,
                              void* d_out, int out_size, void* d_ws, size_t ws_size,
                              hipStream_t stream) {
  const float* v = (const float*)d_in[1];   // only live input
  float* out = (float*)d_out;

  // ws carve (~31 MB): [Gf 32768] f32, [vnfull][vT][vnT] bf16, [Rg] bf16
  float* Gf = (float*)d_ws;
  unsigned short* vnfull = (unsigned short*)(Gf + HEADS * DH * DH);
  unsigned short* vT  = vnfull + (size_t)NN * CC;
  unsigned short* vnT = vT + (size_t)NN * CC;
  unsigned short* Rg  = vnT + (size_t)NN * CC;

  k_prep<<<dim3(HEADS * (NN / 64)), dim3(256), 0, stream>>>(v, vnfull, vT, vnT, out);
  k_rgemm<<<dim3(8 + 325), dim3(256), 0, stream>>>(vnfull, vT, vnT, Gf, Rg);
  k_fused<<<dim3(800 + (NN / 16) * 2), dim3(256), 0, stream>>>(
      Rg, vnfull, Gf, vT, out + (size_t)NN * 2 * CC, out);
}

// Round 5
// 168.072 us; speedup vs baseline: 1.1281x; 1.1281x over previous
//
#include <hip/hip_runtime.h>

// Attention_msa_TwoStream. Only v_cls (d_in[1]) feeds outputs (MLP/q/k dead).
// N=3200, H=8, d=64, C=512; fp32 I/O; bf16 MFMA internals.
// Pipeline (3 dispatches, no memset, no atomics, no K-loop barriers):
//   k_prep  : per-(n,h) L2 norm; vnfull bf16 + vT/vnT transposes + x_ori.
//   k_rgemm : bid 0-15  -> G_h partials (h x K-half), direct-global NT GEMM.
//             bid 16-340-> R = 1/8 vn.vn^T upper-tri 128x128 tiles. vnfull is
//                         3.3 MB (L2-resident) so NO LDS staging: each wave
//                         reads its MFMA frags straight from global with a
//                         register ping-pong prefetch; zero barriers in loop.
//                         Epilogue stages via 32 KB LDS -> full 256B row
//                         writes for both (bi,bj) and (bj,bi).
//   k_fused : rows: Z/E row-sum + normalize -> out2 | tiles: X = vn.(G0+G1) - corr.

#define NN 3200
#define HEADS 8
#define DH 64
#define CC 512

typedef __attribute__((ext_vector_type(8))) short short8;   // 8 bf16
typedef __attribute__((ext_vector_type(4))) float f32x4;

static __device__ __forceinline__ unsigned short f2b(float f) {
  union { float f; unsigned u; } x; x.f = f;
  unsigned r = x.u + 0x7FFFu + ((x.u >> 16) & 1u);   // RTN-even
  return (unsigned short)(r >> 16);
}
static __device__ __forceinline__ float b2f(unsigned short s) {
  union { unsigned u; float f; } x; x.u = ((unsigned)s) << 16; return x.f;
}
static __device__ __forceinline__ short8 pack8(f32x4 lo, f32x4 hi) {
  short8 r;
  r[0] = (short)f2b(lo[0]); r[1] = (short)f2b(lo[1]);
  r[2] = (short)f2b(lo[2]); r[3] = (short)f2b(lo[3]);
  r[4] = (short)f2b(hi[0]); r[5] = (short)f2b(hi[1]);
  r[6] = (short)f2b(hi[2]); r[7] = (short)f2b(hi[3]);
  return r;
}

// ---------------------------------------------------------------------------
// k_prep: per-(n,h) L2 norm; vnfull bf16 (cached - heavy reuse), vT/vnT bf16
// transposes + x_ori f32 (non-temporal - streaming). No atomics, no MFMA.
__global__ __launch_bounds__(256) void k_prep(const float* __restrict__ v,
                                              unsigned short* __restrict__ vnfull,
                                              unsigned short* __restrict__ vT,
                                              unsigned short* __restrict__ vnT,
                                              float* __restrict__ out) {
  __shared__ unsigned short tileV[DH][72];   // [dim][row]
  __shared__ unsigned short tileN[DH][72];
  int h  = blockIdx.x & 7;
  int n0 = (int)(blockIdx.x >> 3) * 64;
  int j  = threadIdx.x & 63;       // dim within head
  int w  = threadIdx.x >> 6;       // wave = row group
  #pragma unroll
  for (int i = 0; i < 16; i++) {
    int n = n0 + w * 16 + i;
    float val = v[(size_t)n * CC + h * DH + j];
    float ss = val * val;
    #pragma unroll
    for (int off = 32; off >= 1; off >>= 1) ss += __shfl_xor(ss, off, 64);
    float inv = 1.0f / (sqrtf(ss) + 1e-8f);
    unsigned short un = f2b(val * inv);
    tileV[j][w * 16 + i] = f2b(val);
    tileN[j][w * 16 + i] = un;
    vnfull[(size_t)n * CC + h * DH + j] = un;
    __builtin_nontemporal_store(val, out + (size_t)n * (2 * CC) + CC + h * DH + j);
  }
  __syncthreads();
  #pragma unroll
  for (int i = 0; i < 16; i++) {
    int jj = w * 16 + i;
    __builtin_nontemporal_store(tileV[jj][j], vT  + ((size_t)h * DH + jj) * NN + n0 + j);
    __builtin_nontemporal_store(tileN[jj][j], vnT + ((size_t)h * DH + jj) * NN + n0 + j);
  }
}

// ---------------------------------------------------------------------------
// k_rgemm: bid 0-15: G_h partials. bid 16-340: upper-tri R tiles, LDS-free
// K-loop (direct global reads from L2-resident vnfull).
__global__ __launch_bounds__(256) void k_rgemm(const unsigned short* __restrict__ vnfull,
                                               const unsigned short* __restrict__ vT,
                                               const unsigned short* __restrict__ vnT,
                                               float* __restrict__ Gf,
                                               unsigned short* __restrict__ Rg) {
  __shared__ __align__(16) unsigned short S[16384];   // 32 KB: epilogue staging only
  int bid = (int)blockIdx.x;
  int tid = threadIdx.x;
  int lane = tid & 63, quad = lane >> 4, l16 = lane & 15;

  if (bid < 16) {
    // ---- G partial: G[half][h][d][k] = sum_{m in half} V[m][d]*vn[m][k] --
    int h = bid >> 1, half = bid & 1, w = tid >> 6;
    int mbase = half * 1600;
    const unsigned short* aP = vT + (size_t)(h * DH + w * 16 + l16) * NN + quad * 8 + mbase;
    const unsigned short* bP[4];
    #pragma unroll
    for (int ct = 0; ct < 4; ct++)
      bP[ct] = vnT + (size_t)(h * DH + ct * 16 + l16) * NN + quad * 8 + mbase;
    f32x4 acc4[4];
    #pragma unroll
    for (int ct = 0; ct < 4; ct++) acc4[ct] = (f32x4){0.f, 0.f, 0.f, 0.f};
    #pragma unroll 2
    for (int m0 = 0; m0 < 1600; m0 += 64) {
      short8 a0 = *(const short8*)(aP + m0);
      short8 a1 = *(const short8*)(aP + m0 + 32);
      #pragma unroll
      for (int ct = 0; ct < 4; ct++) {
        short8 b0 = *(const short8*)(bP[ct] + m0);
        short8 b1 = *(const short8*)(bP[ct] + m0 + 32);
        acc4[ct] = __builtin_amdgcn_mfma_f32_16x16x32_bf16(a0, b0, acc4[ct], 0, 0, 0);
        acc4[ct] = __builtin_amdgcn_mfma_f32_16x16x32_bf16(a1, b1, acc4[ct], 0, 0, 0);
      }
    }
    #pragma unroll
    for (int ct = 0; ct < 4; ct++)
      #pragma unroll
      for (int g = 0; g < 4; g++)
        Gf[(size_t)half * 32768 + h * 4096 +
           (w * 16 + quad * 4 + g) * 64 + ct * 16 + l16] = acc4[ct][g];
    return;
  }
  bid -= 16;

  // upper-triangular (incl. diagonal) tile map: bid -> (bi, bj), bj >= bi
  int bi = 0;
  while (bid >= 25 - bi) { bid -= 25 - bi; bi++; }
  int bj = bi + bid;
  int n0 = bi * 128, m0 = bj * 128;
  int wv = tid >> 6, wr = wv >> 1, wc = wv & 1;

  // per-wave direct-global fragment pointers (rows n/m, cols = K)
  const unsigned short* pA = vnfull + (size_t)(n0 + wr * 64 + l16) * CC + quad * 8;
  const unsigned short* pB = vnfull + (size_t)(m0 + wc * 64 + l16) * CC + quad * 8;

  f32x4 acc[4][4];
  #pragma unroll
  for (int rt = 0; rt < 4; rt++)
    #pragma unroll
    for (int ct = 0; ct < 4; ct++) acc[rt][ct] = (f32x4){0.f, 0.f, 0.f, 0.f};

#define LOADK(A_, B_, KK)                                                     \
  do {                                                                        \
    _Pragma("unroll")                                                         \
    for (int rt = 0; rt < 4; rt++)                                            \
      A_[rt] = *(const short8*)(pA + rt * 16 * CC + (KK) * 32);               \
    _Pragma("unroll")                                                         \
    for (int ct = 0; ct < 4; ct++)                                            \
      B_[ct] = *(const short8*)(pB + ct * 16 * CC + (KK) * 32);               \
  } while (0)

#define MFMAK(A_, B_)                                                         \
  do {                                                                        \
    _Pragma("unroll")                                                         \
    for (int rt = 0; rt < 4; rt++)                                            \
      _Pragma("unroll")                                                       \
      for (int ct = 0; ct < 4; ct++)                                          \
        acc[rt][ct] = __builtin_amdgcn_mfma_f32_16x16x32_bf16(A_[rt], B_[ct], \
                                                              acc[rt][ct],    \
                                                              0, 0, 0);       \
  } while (0)

  // register ping-pong: loads for step k+1 in flight under step k's MFMAs
  short8 aP4[4], bP4[4], aQ4[4], bQ4[4];
  LOADK(aP4, bP4, 0);
  #pragma unroll
  for (int kp = 0; kp < 7; kp++) {
    LOADK(aQ4, bQ4, 2 * kp + 1);
    MFMAK(aP4, bP4);
    LOADK(aP4, bP4, 2 * kp + 2);
    MFMAK(aQ4, bQ4);
  }
  LOADK(aQ4, bQ4, 15);
  MFMAK(aP4, bP4);
  MFMAK(aQ4, bQ4);
#undef LOADK
#undef MFMAK

  // ---- epilogue A: orientation (n,m) — swizzled LDS stage + row writes ---
  // Tile element (r,c) at S[r*128 + ((c>>3)^quad)*8 + (c&7)], quad==(r>>2)&3.
  #pragma unroll
  for (int rt = 0; rt < 4; rt++) {
    int rbase = wr * 64 + rt * 16 + quad * 4;
    #pragma unroll
    for (int g = 0; g < 4; g++) {
      int r = rbase + g;
      int n = n0 + r;
      int bs = (n / 10) * 10;
      #pragma unroll
      for (int ct = 0; ct < 4; ct++) {
        int c = wc * 64 + ct * 16 + l16;
        int m = m0 + c;
        float R = acc[rt][ct][g] * 0.125f;
        float eR = __expf(R);
        bool sel = (R > 0.75f);
        bool zz = (m >= bs) & (m < bs + 9) & (m != n);
        float ef = zz ? 1.0f : eR;            // exp(0)=1
        S[r * 128 + (((c >> 3) ^ quad) << 3) + (c & 7)] = f2b(sel ? ef : -ef);
      }
    }
  }
  __syncthreads();
  {
    int r2b = wv * 32 + (lane >> 4);
    int s_ = lane & 15;
    #pragma unroll
    for (int i = 0; i < 8; i++) {
      int r2 = r2b + i * 4;
      int k = s_ ^ ((r2 >> 2) & 3);
      short8 vvv = *(const short8*)&S[r2 * 128 + s_ * 8];
      *(short8*)(Rg + (size_t)(n0 + r2) * NN + m0 + k * 8) = vvv;   // temporal: ride L3
    }
  }

  if (bi != bj) {
    // ---- epilogue B: orientation (m,n) — transposed staging --------------
    // Element (r,c) -> S[c*128 + ((r>>3)^l16)*8 + (r&7)], l16 == c&15.
    __syncthreads();
    #pragma unroll
    for (int rt = 0; rt < 4; rt++) {
      int rbase = wr * 64 + rt * 16 + quad * 4;
      #pragma unroll
      for (int g = 0; g < 4; g++) {
        int r = rbase + g;
        int n = n0 + r;
        #pragma unroll
        for (int ct = 0; ct < 4; ct++) {
          int c = wc * 64 + ct * 16 + l16;
          int m = m0 + c;
          int bsm = (m / 10) * 10;
          float R = acc[rt][ct][g] * 0.125f;
          float eR = __expf(R);
          bool sel = (R > 0.75f);
          bool zz = (n >= bsm) & (n < bsm + 9) & (m != n);
          float ef = zz ? 1.0f : eR;
          S[c * 128 + (((r >> 3) ^ l16) << 3) + (r & 7)] = f2b(sel ? ef : -ef);
        }
      }
    }
    __syncthreads();
    int r2b = wv * 32 + (lane >> 4);
    int s_ = lane & 15;
    #pragma unroll
    for (int i = 0; i < 8; i++) {
      int r2 = r2b + i * 4;                  // output row = m0 + r2
      int k = s_ ^ (r2 & 15);
      short8 vvv = *(const short8*)&S[r2 * 128 + s_ * 8];
      *(short8*)(Rg + (size_t)(m0 + r2) * NN + n0 + k * 8) = vvv;
    }
  }
}

// ---------------------------------------------------------------------------
// k_fused: blocks [0,800): out2 rows (wave-per-row Z/E sum + normalize);
//          blocks [800,1200): k_x tiles (X = vn.(G0+G1) - zone corr).
__global__ __launch_bounds__(256) void k_fused(const unsigned short* __restrict__ Rg,
                                               const unsigned short* __restrict__ vnfull,
                                               const float* __restrict__ Gf,
                                               const unsigned short* __restrict__ vT,
                                               float* __restrict__ out2,
                                               float* __restrict__ out) {
  int bid = (int)blockIdx.x;
  if (bid < 800) {
    // ---- softmax rows: n = bid*4 + wave ---------------------------------
    int w = threadIdx.x >> 6, lane = threadIdx.x & 63;
    int n = bid * 4 + w;
    const unsigned short* rp = Rg + (size_t)n * NN;
    short8 s[7];
    float z = 0.f, e = 0.f;
    #pragma unroll
    for (int i = 0; i < 7; i++) {
      int c = lane + i * 64;              // chunk of 8 bf16; 400 chunks/row
      if (c < 400) {
        s[i] = *(const short8*)(rp + c * 8);   // temporal: L3 hit after k_rgemm
        #pragma unroll
        for (int j = 0; j < 8; j++) {
          float val = b2f((unsigned short)s[i][j]);
          z += fabsf(val);
          e += fmaxf(val, 0.f);
        }
      }
    }
    #pragma unroll
    for (int off = 1; off <= 32; off <<= 1) {
      z += __shfl_xor(z, off, 64);
      e += __shfl_xor(e, off, 64);
    }
    float rd = 1.0f / (e + 1e-8f * z);
    float* op = out2 + (size_t)n * NN;
    #pragma unroll
    for (int i = 0; i < 7; i++) {
      int c = lane + i * 64;
      if (c < 400) {
        f32x4 o0, o1;
        #pragma unroll
        for (int j = 0; j < 4; j++) {
          float a = b2f((unsigned short)s[i][j]);
          o0[j] = (a > 0.f) ? a * rd : 0.f;
          float b = b2f((unsigned short)s[i][4 + j]);
          o1[j] = (b > 0.f) ? b * rd : 0.f;
        }
        __builtin_nontemporal_store(o0, (f32x4*)(op + c * 8));
        __builtin_nontemporal_store(o1, (f32x4*)(op + c * 8 + 4));
      }
    }
  } else {
    // ---- X tiles: X_h[n][d] = vn.G - zone correction --------------------
    bid -= 800;
    __shared__ __align__(16) unsigned short Sz[4][16][48];
    int hl   = threadIdx.x >> 6;
    int h    = (bid & 1) * 4 + hl;
    int lane = threadIdx.x & 63;
    int quad = lane >> 4, l16 = lane & 15;
    int n0 = (bid >> 1) * 16;
    int lo = (n0 / 10) * 10;                    // zone window [lo, lo+32)

    short8 aZ[2];
    #pragma unroll
    for (int kh = 0; kh < 2; kh++)
      aZ[kh] = *(const short8*)(vnfull + (size_t)(n0 + l16) * CC + h * DH + kh * 32 + quad * 8);

    #pragma unroll
    for (int ct = 0; ct < 2; ct++) {
      int rB = lo + ct * 16 + l16;
      int rC = rB < NN ? rB : NN - 1;           // clamp OOB (mask kills it)
      short8 b0 = *(const short8*)(vnfull + (size_t)rC * CC + h * DH + quad * 8);
      short8 b1 = *(const short8*)(vnfull + (size_t)rC * CC + h * DH + 32 + quad * 8);
      f32x4 cS = (f32x4){0.f, 0.f, 0.f, 0.f};
      cS = __builtin_amdgcn_mfma_f32_16x16x32_bf16(aZ[0], b0, cS, 0, 0, 0);
      cS = __builtin_amdgcn_mfma_f32_16x16x32_bf16(aZ[1], b1, cS, 0, 0, 0);
      int m = lo + ct * 16 + l16;
      #pragma unroll
      for (int g = 0; g < 4; g++) {
        int n = n0 + quad * 4 + g;
        int bs = (n / 10) * 10;
        bool keep = (m >= bs) & (m < bs + 9) & (m != n);
        Sz[hl][quad * 4 + g][ct * 16 + l16] = f2b(keep ? -cS[g] : 0.f);
      }
    }
    __syncthreads();

    f32x4 xr[4];
    #pragma unroll
    for (int nt = 0; nt < 4; nt++) {
      const float* gp = Gf + (size_t)h * 4096 + (nt * 16 + l16) * 64 + quad * 8;
      f32x4 lo0 = *(const f32x4*)gp        + *(const f32x4*)(gp + 32768);
      f32x4 hi0 = *(const f32x4*)(gp + 4)  + *(const f32x4*)(gp + 4 + 32768);
      f32x4 lo1 = *(const f32x4*)(gp + 32) + *(const f32x4*)(gp + 32 + 32768);
      f32x4 hi1 = *(const f32x4*)(gp + 36) + *(const f32x4*)(gp + 36 + 32768);
      short8 g0 = pack8(lo0, hi0);
      short8 g1 = pack8(lo1, hi1);
      f32x4 cX = (f32x4){0.f, 0.f, 0.f, 0.f};
      cX = __builtin_amdgcn_mfma_f32_16x16x32_bf16(aZ[0], g0, cX, 0, 0, 0);
      cX = __builtin_amdgcn_mfma_f32_16x16x32_bf16(aZ[1], g1, cX, 0, 0, 0);
      xr[nt] = cX;
    }

    short8 aC = *(const short8*)&Sz[hl][l16][quad * 8];
    #pragma unroll
    for (int nt = 0; nt < 4; nt++) {
      short8 b = *(const short8*)(vT + (size_t)(h * DH + nt * 16 + l16) * NN + lo + quad * 8);
      xr[nt] = __builtin_amdgcn_mfma_f32_16x16x32_bf16(aC, b, xr[nt], 0, 0, 0);
    }

    #pragma unroll
    for (int nt = 0; nt < 4; nt++)
      #pragma unroll
      for (int g = 0; g < 4; g++)
        __builtin_nontemporal_store(xr[nt][g],
            out + (size_t)(n0 + quad * 4 + g) * (2 * CC) + h * DH + nt * 16 + l16);
  }
}

// ---------------------------------------------------------------------------
extern "C" void kernel_launch(void* const* d_in, const int* in_sizes, int n_in,
                              void* d_out, int out_size, void* d_ws, size_t ws_size,
                              hipStream_t stream) {
  const float* v = (const float*)d_in[1];   // only live input
  float* out = (float*)d_out;

  // ws carve (~31 MB): [Gf 2x32768] f32, [vnfull][vT][vnT] bf16, [Rg] bf16
  float* Gf = (float*)d_ws;
  unsigned short* vnfull = (unsigned short*)(Gf + 2 * HEADS * DH * DH);
  unsigned short* vT  = vnfull + (size_t)NN * CC;
  unsigned short* vnT = vT + (size_t)NN * CC;
  unsigned short* Rg  = vnT + (size_t)NN * CC;

  k_prep<<<dim3(HEADS * (NN / 64)), dim3(256), 0, stream>>>(v, vnfull, vT, vnT, out);
  k_rgemm<<<dim3(16 + 325), dim3(256), 0, stream>>>(vnfull, vT, vnT, Gf, Rg);
  k_fused<<<dim3(800 + (NN / 16) * 2), dim3(256), 0, stream>>>(
      Rg, vnfull, Gf, vT, out + (size_t)NN * 2 * CC, out);
}